// Round 1
// baseline (3315.762 us; speedup 1.0000x reference)
//
#include <hip/hip_runtime.h>
#include <hip/hip_bf16.h>

#define T_STEPS 512
#define BATCH   256
#define DIM     256
#define HID     256
#define BR      32
#define BC      32
#define NC      8   // col-block WGs per row group

using bf16x8  = __attribute__((ext_vector_type(8))) __bf16;
using bf16x4  = __attribute__((ext_vector_type(4))) __bf16;
using f32x16  = __attribute__((ext_vector_type(16))) float;
using floatx4 = __attribute__((ext_vector_type(4))) float;

__device__ __forceinline__ float sigf(float x)   { return 1.0f / (1.0f + __expf(-x)); }
__device__ __forceinline__ float tanh_f(float x) { return 1.0f - 2.0f / (1.0f + __expf(2.0f * x)); }

__global__ void init_ws(const float* __restrict__ h0, float* __restrict__ hbuf0,
                        int* __restrict__ bar) {
  int i = blockIdx.x * 256 + threadIdx.x;
  if (i < BATCH * HID) hbuf0[i] = h0[i];
  if (i < 4096) bar[i] = 0;
}

__global__ __launch_bounds__(256, 1) void lstm_persist(
    const float* __restrict__ x, const float* __restrict__ c0,
    const float* __restrict__ mask_x, const float* __restrict__ mask_h,
    const float* __restrict__ W_ih, const float* __restrict__ W_hh,
    const float* __restrict__ b_ih, const float* __restrict__ b_hh,
    const int* __restrict__ bs_g,
    float* __restrict__ out, float* __restrict__ hn_out, float* __restrict__ cn_out,
    float* __restrict__ hbuf0, float* __restrict__ hbuf1, int* __restrict__ bar) {

  const int tid = threadIdx.x;
  const int g   = blockIdx.x & 7;   // row group (XCD-co-located under round-robin)
  const int j   = blockIdx.x >> 3;  // col block
  const int row_base = g * BR;
  const int col_base = j * BC;
  const int lane = tid & 63;
  const int wv   = tid >> 6;        // wave id == gate id (i,f,g,o)
  const int lrow = lane & 31;
  const int half = lane >> 5;

  __shared__ alignas(16) __bf16 s_xi[BR * DIM];     // 16 KB, XOR-swizzled bf16
  __shared__ alignas(16) __bf16 s_hi[BR * HID];     // 16 KB
  __shared__ alignas(16) float  s_gates[4][BR * BC];// 16 KB
  __shared__ alignas(16) float  s_bias[4][BC];
  __shared__ int s_bs[T_STEPS];

  for (int i = tid; i < T_STEPS; i += 256) s_bs[i] = bs_g[i];
  if (tid < 4 * BC) {
    int q = tid >> 5, c = tid & 31;
    int grow = q * HID + col_base + c;
    s_bias[q][c] = b_ih[grow] + b_hh[grow];
  }

  // Stationary W fragments -> registers (B-operand of mfma_f32_32x32x16_bf16).
  // B[k][n]: n = lane&31 (local gate col), k = m*16 + 8*(lane>>5) + e.
  bf16x8 wih_f[16], whh_f[16];
  {
    const size_t wr = (size_t)(wv * HID + col_base + lrow) * DIM;
    #pragma unroll
    for (int m = 0; m < 16; ++m) {
      const int k0 = m * 16 + 8 * half;
      floatx4 a0 = *(const floatx4*)(W_ih + wr + k0);
      floatx4 a1 = *(const floatx4*)(W_ih + wr + k0 + 4);
      bf16x8 f;
      f[0]=(__bf16)a0[0]; f[1]=(__bf16)a0[1]; f[2]=(__bf16)a0[2]; f[3]=(__bf16)a0[3];
      f[4]=(__bf16)a1[0]; f[5]=(__bf16)a1[1]; f[6]=(__bf16)a1[2]; f[7]=(__bf16)a1[3];
      wih_f[m] = f;
      floatx4 b0 = *(const floatx4*)(W_hh + wr + k0);
      floatx4 b1 = *(const floatx4*)(W_hh + wr + k0 + 4);
      bf16x8 h;
      h[0]=(__bf16)b0[0]; h[1]=(__bf16)b0[1]; h[2]=(__bf16)b0[2]; h[3]=(__bf16)b0[3];
      h[4]=(__bf16)b1[0]; h[5]=(__bf16)b1[1]; h[6]=(__bf16)b1[2]; h[7]=(__bf16)b1[3];
      whh_f[m] = h;
    }
  }

  // Variational dropout masks for this thread's staging slice -> registers (f32).
  floatx4 mx[8], mh[8];
  #pragma unroll
  for (int i = 0; i < 8; ++i) {
    const int e = tid * 4 + i * 1024;
    mx[i] = *(const floatx4*)(mask_x + row_base * DIM + e);
    mh[i] = *(const floatx4*)(mask_h + row_base * HID + e);
  }

  const int crow = row_base + (tid >> 3);
  const int ccol = col_base + (tid & 7) * 4;
  floatx4 c_reg = *(const floatx4*)(c0 + crow * HID + ccol);
  floatx4 h_last; h_last[0]=h_last[1]=h_last[2]=h_last[3]=0.0f;

  int* cnt = bar + g * 64;
  int* flg = bar + g * 64 + 32;

  __syncthreads();

  const float* hcur = hbuf0;
  float* hnext = hbuf1;

  // prefetch x tile for t=0
  floatx4 xv[8];
  if (s_bs[0] > row_base) {
    const float* xblk = x + (size_t)row_base * DIM;
    #pragma unroll
    for (int i = 0; i < 8; ++i) xv[i] = *(const floatx4*)(xblk + tid * 4 + i * 1024);
  }

  for (int t = 0; t < T_STEPS; ++t) {
    const int bsz = s_bs[t];
    if (bsz > row_base) {
      // ---- stage activations (mask-mul, f32->bf16, swizzled LDS) ----
      const float* hblk = hcur + row_base * HID;
      floatx4 hv[8];
      #pragma unroll
      for (int i = 0; i < 8; ++i) hv[i] = *(const floatx4*)(hblk + tid * 4 + i * 1024);
      #pragma unroll
      for (int i = 0; i < 8; ++i) {
        const int e = tid * 4 + i * 1024;
        const int r = e >> 8, k = e & 255;
        const int off = ((r * 512 + k * 2) ^ ((r & 7) << 4));
        floatx4 xm = xv[i] * mx[i];
        bf16x4 xb; xb[0]=(__bf16)xm[0]; xb[1]=(__bf16)xm[1]; xb[2]=(__bf16)xm[2]; xb[3]=(__bf16)xm[3];
        *(bf16x4*)((char*)s_xi + off) = xb;
      }
      #pragma unroll
      for (int i = 0; i < 8; ++i) {
        const int e = tid * 4 + i * 1024;
        const int r = e >> 8, k = e & 255;
        const int off = ((r * 512 + k * 2) ^ ((r & 7) << 4));
        floatx4 hm = hv[i] * mh[i];
        bf16x4 hb; hb[0]=(__bf16)hm[0]; hb[1]=(__bf16)hm[1]; hb[2]=(__bf16)hm[2]; hb[3]=(__bf16)hm[3];
        *(bf16x4*)((char*)s_hi + off) = hb;
      }
      __syncthreads();

      // ---- MFMA: gates tile = act(32x256) @ W^T(256x32), two indep chains ----
      f32x16 accx, acch;
      #pragma unroll
      for (int z = 0; z < 16; ++z) { accx[z] = 0.0f; acch[z] = 0.0f; }
      const int xorv  = (lrow & 7) << 4;
      const int abase = lrow * 512 + half * 16;
      #pragma unroll
      for (int m = 0; m < 16; ++m) {
        bf16x8 ax = *(const bf16x8*)((const char*)s_xi + ((abase + m * 32) ^ xorv));
        bf16x8 ah = *(const bf16x8*)((const char*)s_hi + ((abase + m * 32) ^ xorv));
        accx = __builtin_amdgcn_mfma_f32_32x32x16_bf16(ax, wih_f[m], accx, 0, 0, 0);
        acch = __builtin_amdgcn_mfma_f32_32x32x16_bf16(ah, whh_f[m], acch, 0, 0, 0);
      }
      // C/D layout: col = lane&31, row = (reg&3) + 8*(reg>>2) + 4*(lane>>5)
      #pragma unroll
      for (int rr = 0; rr < 16; ++rr) {
        const int row = (rr & 3) + 8 * (rr >> 2) + 4 * half;
        s_gates[wv][row * BC + lrow] = accx[rr] + acch[rr];
      }
      __syncthreads();

      // ---- LSTM cell (fp32) ----
      {
        const int row = tid >> 3, c4 = (tid & 7) * 4;
        const bool active = (row_base + row) < bsz;
        floatx4 gi = *(const floatx4*)&s_gates[0][row * BC + c4];
        floatx4 gf = *(const floatx4*)&s_gates[1][row * BC + c4];
        floatx4 gg = *(const floatx4*)&s_gates[2][row * BC + c4];
        floatx4 go = *(const floatx4*)&s_gates[3][row * BC + c4];
        floatx4 bi = *(const floatx4*)&s_bias[0][c4];
        floatx4 bf = *(const floatx4*)&s_bias[1][c4];
        floatx4 bg = *(const floatx4*)&s_bias[2][c4];
        floatx4 bo = *(const floatx4*)&s_bias[3][c4];
        floatx4 h_old = *(const floatx4*)(hcur + crow * HID + ccol);
        floatx4 hout, oout, cnew;
        #pragma unroll
        for (int e2 = 0; e2 < 4; ++e2) {
          float iv = sigf(gi[e2] + bi[e2]);
          float fv = sigf(gf[e2] + bf[e2]);
          float gv = tanh_f(gg[e2] + bg[e2]);
          float ov = sigf(go[e2] + bo[e2]);
          float cc = fv * c_reg[e2] + iv * gv;
          float hh = ov * tanh_f(cc);
          cnew[e2] = cc;
          hout[e2] = active ? hh : h_old[e2];
          oout[e2] = active ? hh : 0.0f;
        }
        if (active) c_reg = cnew;
        h_last = hout;
        *(floatx4*)(hnext + crow * HID + ccol) = hout;
        *(floatx4*)(out + ((size_t)t * BATCH + crow) * HID + ccol) = oout;
      }
    } else {
      // whole row-block inactive: write-through h, zero output
      floatx4 h_old = *(const floatx4*)(hcur + crow * HID + ccol);
      h_last = h_old;
      *(floatx4*)(hnext + crow * HID + ccol) = h_old;
      floatx4 z; z[0]=z[1]=z[2]=z[3]=0.0f;
      *(floatx4*)(out + ((size_t)t * BATCH + crow) * HID + ccol) = z;
    }

    // prefetch next x tile (independent of h) to hide HBM latency under barrier
    if (t + 1 < T_STEPS && s_bs[t + 1] > row_base) {
      const float* xblk = x + ((size_t)(t + 1) * BATCH + row_base) * DIM;
      #pragma unroll
      for (int i = 0; i < 8; ++i) xv[i] = *(const floatx4*)(xblk + tid * 4 + i * 1024);
    }

    // ---- per-group barrier (8 WGs), epoch-counting, device scope ----
    __syncthreads();
    if (tid == 0) {
      __builtin_amdgcn_fence(__ATOMIC_RELEASE, "agent");
      int prev = __hip_atomic_fetch_add(cnt, 1, __ATOMIC_RELAXED, __HIP_MEMORY_SCOPE_AGENT);
      if (prev == NC - 1) {
        __hip_atomic_store(cnt, 0, __ATOMIC_RELAXED, __HIP_MEMORY_SCOPE_AGENT);
        __hip_atomic_store(flg, t + 1, __ATOMIC_RELEASE, __HIP_MEMORY_SCOPE_AGENT);
      } else {
        while (__hip_atomic_load(flg, __ATOMIC_ACQUIRE, __HIP_MEMORY_SCOPE_AGENT) < t + 1) {
          __builtin_amdgcn_s_sleep(1);
        }
      }
      __builtin_amdgcn_fence(__ATOMIC_ACQUIRE, "agent");
    }
    __syncthreads();

    const float* tmp = hnext; hnext = (float*)hcur; hcur = tmp;
  }

  // epilogue: carry state
  *(floatx4*)(hn_out + crow * HID + ccol) = h_last;
  *(floatx4*)(cn_out + crow * HID + ccol) = c_reg;
}

extern "C" void kernel_launch(void* const* d_in, const int* in_sizes, int n_in,
                              void* d_out, int out_size, void* d_ws, size_t ws_size,
                              hipStream_t stream) {
  const float* x      = (const float*)d_in[0];
  const float* h0     = (const float*)d_in[1];
  const float* c0     = (const float*)d_in[2];
  const float* mask_x = (const float*)d_in[3];
  const float* mask_h = (const float*)d_in[4];
  const float* W_ih   = (const float*)d_in[5];
  const float* W_hh   = (const float*)d_in[6];
  const float* b_ih   = (const float*)d_in[7];
  const float* b_hh   = (const float*)d_in[8];
  const int*   bs     = (const int*)d_in[9];

  float* out = (float*)d_out;
  float* hn  = out + (size_t)T_STEPS * BATCH * HID;
  float* cn  = hn + (size_t)BATCH * HID;

  int*   bar   = (int*)d_ws;                         // 16 KB barrier region
  float* hbuf0 = (float*)((char*)d_ws + 16384);      // B*H f32
  float* hbuf1 = hbuf0 + (size_t)BATCH * HID;        // B*H f32

  init_ws<<<256, 256, 0, stream>>>(h0, hbuf0, bar);
  lstm_persist<<<64, 256, 0, stream>>>(x, c0, mask_x, mask_h, W_ih, W_hh,
                                       b_ih, b_hh, bs, out, hn, cn,
                                       hbuf0, hbuf1, bar);
}